// Round 7
// baseline (3808.751 us; speedup 1.0000x reference)
//
#include <hip/hip_runtime.h>

typedef unsigned short u16;
typedef unsigned int uint;

using f32x4 = __attribute__((ext_vector_type(4))) float;
using bf16x8 = __attribute__((ext_vector_type(8))) __bf16;

static __device__ __forceinline__ bf16x8 as_bf16x8(uint4 u) {
    union { uint4 a; bf16x8 b; } c; c.a = u; return c.b;
}
static __device__ __forceinline__ float bf2f(u16 h) {
    union { uint u; float f; } c; c.u = ((uint)h) << 16; return c.f;
}
static __device__ __forceinline__ u16 f2bf(float f) {
    union { float f; uint u; } c; c.f = f;
    uint u = c.u;
    return (u16)((u + 0x7fffu + ((u >> 16) & 1u)) >> 16);
}
static __device__ __forceinline__ float fast_sigmoid(float x) {
    x = fminf(30.f, fmaxf(-30.f, x));
    return __builtin_amdgcn_rcpf(1.0f + __builtin_amdgcn_exp2f(x * -1.44269504f));
}
static __device__ __forceinline__ float fast_tanh(float x) {
    x = fminf(15.f, fmaxf(-15.f, x));
    return 1.0f - 2.0f * __builtin_amdgcn_rcpf(1.0f + __builtin_amdgcn_exp2f(x * 2.88539008f));
}

// dtype detector (fp32 vs bf16 buffers) — deterministic, graph-capture safe.
static __device__ __forceinline__ int detect_fp32(const uint* w, int nwords) {
    int hits = 0;
    for (int i = 0; i < nwords; ++i) { uint e = (w[i] >> 7) & 0xffu; hits += (e >= 0x80u); }
    return hits > (nwords >> 3);
}
static __device__ __forceinline__ u16 load_bf(const void* p, int i, int fp32) {
    return fp32 ? f2bf(((const float*)p)[i]) : ((const u16*)p)[i];
}

// Fragment-ordered weight pack:
//   wp[((w*KSTEPS + ks)*4 + nt)*512 + lane*8 + j]
//   n = w*64 + nt*16 + (lane&15) = 4*unit + gate;  k = ks*32 + (lane>>4)*8 + j
__global__ void pack_w(const void* wf, const void* wi, const void* wc, const void* wo,
                       const void* bbf, const void* bbi, const void* bbc, const void* bbo,
                       u16* __restrict__ wp, u16* __restrict__ bp, int K, int KSTEPS) {
    __shared__ int sfp;
    if (threadIdx.x == 0) sfp = detect_fp32((const uint*)wf, 256);
    __syncthreads();
    const int fp32 = sfp;
    int w = blockIdx.x / KSTEPS, ks = blockIdx.x % KSTEPS;
    int nt = threadIdx.x >> 6, lane = threadIdx.x & 63;
    int c16 = lane & 15, q = lane >> 4;
    int n = w * 64 + nt * 16 + c16;
    int u = n >> 2, g = n & 3;
    const void* W = (g == 0) ? wf : (g == 1) ? wi : (g == 2) ? wc : wo;
    union { u16 v[8]; uint4 u4; } tmp;
#pragma unroll
    for (int j = 0; j < 8; ++j) {
        int k = ks * 32 + q * 8 + j;
        tmp.v[j] = (k < K) ? load_bf(W, k * 256 + u, fp32) : (u16)0;
    }
    *(uint4*)(wp + ((w * KSTEPS + ks) * 4 + nt) * 512 + lane * 8) = tmp.u4;
    if (ks == 0 && threadIdx.x < 64) {
        int n2 = w * 64 + threadIdx.x;
        int g2 = n2 & 3;
        const void* B = (g2 == 0) ? bbf : (g2 == 1) ? bbi : (g2 == 2) ? bbc : bbo;
        bp[n2] = load_bf(B, n2 >> 2, fp32);
    }
}

__global__ void pack_out(const void* w_out, const void* b_out,
                         u16* __restrict__ wob, u16* __restrict__ bob) {
    __shared__ int sfp;
    if (threadIdx.x == 0) sfp = detect_fp32((const uint*)w_out, 128);
    __syncthreads();
    if (threadIdx.x < 256) wob[threadIdx.x] = load_bf(w_out, threadIdx.x, sfp);
    if (threadIdx.x == 0) bob[0] = load_bf(b_out, 0, sfp);
}

// Pre-gather x embeddings into dense per-block layout: xd[((grp*80+t)*16+r)*100 + e]
__global__ void pregather_x(const int* __restrict__ tokens, const void* __restrict__ emb,
                            u16* __restrict__ xd) {
    __shared__ int sfp;
    if (threadIdx.x == 0) sfp = detect_fp32((const uint*)emb, 256);
    __syncthreads();
    const int efp = sfp;
    const int grp = blockIdx.x;
    const int r = threadIdx.x >> 5, s = threadIdx.x & 31;
    if (s >= 25) return;
    for (int t = 0; t < 80; ++t) {
        int tok = tokens[(grp * 16 + r) * 80 + t];
        ushort4 xv;
        if (efp) {
            float4 f = *(const float4*)((const float*)emb + tok * 100 + s * 4);
            xv.x = f2bf(f.x); xv.y = f2bf(f.y); xv.z = f2bf(f.z); xv.w = f2bf(f.w);
        } else {
            xv = *(const ushort4*)((const u16*)emb + tok * 100 + s * 4);
        }
        *(ushort4*)(xd + ((grp * 80 + t) * 16 + r) * 100 + s * 4) = xv;
    }
}

#define HX1S 392   // 384 K-cols + 8 pad
#define HX2S 520   // 512 K-cols + 8 pad
#define SCRS 68    // 64 gate-cols + 4 pad

// Register-resident weights: all 12 wp1 chunks (48 uint4/lane) + first 10 wp2
// chunks (40 uint4/lane) live in VGPRs for the whole kernel; wp2 chunks 10..15
// stream per step with a depth-3 rotation (L2-resident: 3 MB/XCD residual set).
__global__ void __launch_bounds__(1024, 1)
lstm_kernel(const u16* __restrict__ xd,
            const u16* __restrict__ wp1, const u16* __restrict__ b1p,
            const u16* __restrict__ wp2, const u16* __restrict__ b2p,
            const u16* __restrict__ wob, const u16* __restrict__ bob,
            float* __restrict__ out) {
    __shared__ __align__(16) u16 hx1[16 * HX1S];        // [r][ h1(256) | x(100) | 0 ]
    __shared__ __align__(16) u16 hx2[16 * HX2S];        // [r][ h2(256) | h1(256) ]
    __shared__ __align__(16) u16 scr[16 * 16 * SCRS];   // per-wave Z scratch

    const int tid = threadIdx.x;
    const int lane = tid & 63;
    const int w = tid >> 6;          // wave 0..15 -> gate-cols [64w, 64w+64)
    const int c16 = lane & 15;
    const int q = lane >> 4;
    const int grp = blockIdx.x;
    const int row0 = grp * 16;

    const int ul = lane & 15;        // unit-local for gates
    const int U = w * 16 + ul;       // global unit 0..255

    // ---- one-time: load resident weight slabs into registers ----
    const u16* w1slab = wp1 + w * (12 * 4 * 512) + lane * 8;
    const u16* w2slab = wp2 + w * (16 * 4 * 512) + lane * 8;
    uint4 w1r[48];   // [ks*4+nt], ks 0..11
    uint4 w2r[40];   // [ks*4+nt], ks 0..9
#pragma unroll
    for (int i = 0; i < 48; ++i) w1r[i] = *(const uint4*)(w1slab + i * 512);
#pragma unroll
    for (int i = 0; i < 40; ++i) w2r[i] = *(const uint4*)(w2slab + i * 512);

    {
        uint* p1 = (uint*)hx1;
        for (int i = tid; i < 16 * HX1S / 2; i += 1024) p1[i] = 0;
        uint* p2 = (uint*)hx2;
        for (int i = tid; i < 16 * HX2S / 2; i += 1024) p2[i] = 0;
    }
    float c1s[4], c2s[4];
#pragma unroll
    for (int j = 0; j < 4; ++j) { c1s[j] = 0.f; c2s[j] = 0.f; }

    // x(t=0) from dense buffer
    const int xr = tid >> 5, xs = tid & 31;
    const bool xth = (tid < 512) && (xs < 25);
    if (xth) {
        ushort4 v = *(const ushort4*)(xd + ((grp * 80 + 0) * 16 + xr) * 100 + xs * 4);
        *(ushort4*)(hx1 + xr * HX1S + 256 + xs * 4) = v;
    }
    ushort4 bw1 = *(const ushort4*)(b1p + U * 4);
    ushort4 bw2 = *(const ushort4*)(b2p + U * 4);
    const float b1f0 = bf2f(bw1.x), b1f1 = bf2f(bw1.y), b1f2 = bf2f(bw1.z), b1f3 = bf2f(bw1.w);
    const float b2f0 = bf2f(bw2.x), b2f1 = bf2f(bw2.y), b2f2 = bf2f(bw2.z), b2f3 = bf2f(bw2.w);

    __syncthreads();

    u16* sw = scr + w * 16 * SCRS;
    const u16* aptr1 = hx1 + c16 * HX1S + q * 8;
    const u16* aptr2 = hx2 + c16 * HX2S + q * 8;

#pragma unroll 1
    for (int t = 0; t < 80; ++t) {
        // x(t+1) load issued early — latency hidden under L1 GEMM
        ushort4 xv;
        bool xact = xth && (t < 79);
        if (xact) xv = *(const ushort4*)(xd + ((grp * 80 + t + 1) * 16 + xr) * 100 + xs * 4);

        // ---------- Layer 1 GEMM (weights fully in registers) ----------
        f32x4 acc[4];
#pragma unroll
        for (int nt = 0; nt < 4; ++nt) acc[nt] = (f32x4){0.f, 0.f, 0.f, 0.f};
        {
            uint4 av[2];
            av[0] = *(const uint4*)(aptr1);
#pragma unroll
            for (int ks = 0; ks < 12; ++ks) {
                if (ks + 1 < 12) av[(ks + 1) & 1] = *(const uint4*)(aptr1 + (ks + 1) * 32);
                bf16x8 a = as_bf16x8(av[ks & 1]);
#pragma unroll
                for (int nt = 0; nt < 4; ++nt)
                    acc[nt] = __builtin_amdgcn_mfma_f32_16x16x32_bf16(a, as_bf16x8(w1r[ks * 4 + nt]), acc[nt], 0, 0, 0);
            }
        }
#pragma unroll
        for (int nt = 0; nt < 4; ++nt)
#pragma unroll
            for (int j = 0; j < 4; ++j)
                sw[(q * 4 + j) * SCRS + nt * 16 + c16] = f2bf(acc[nt][j]);
        __syncthreads();  // B1

        // ---------- gates 1 ----------
#pragma unroll
        for (int j = 0; j < 4; ++j) {
            int r = q * 4 + j;
            ushort4 zz = *(const ushort4*)(sw + r * SCRS + ul * 4);
            float gf = fast_sigmoid(bf2f(zz.x) + b1f0);
            float gi = fast_sigmoid(bf2f(zz.y) + b1f1);
            float gc = fast_tanh(bf2f(zz.z) + b1f2);
            float go = fast_sigmoid(bf2f(zz.w) + b1f3);
            float cn = gf * c1s[j] + gi * gc;
            c1s[j] = cn;
            u16 hb = f2bf(go * fast_tanh(cn));
            hx1[r * HX1S + U] = hb;
            hx2[r * HX2S + 256 + U] = hb;
        }
        if (xact) *(ushort4*)(hx1 + xr * HX1S + 256 + xs * 4) = xv;
        __syncthreads();  // B2

        // ---------- Layer 2 GEMM (ks 0..9 registers, 10..15 streamed) ----------
        f32x4 acc2[4];
#pragma unroll
        for (int nt = 0; nt < 4; ++nt) acc2[nt] = (f32x4){0.f, 0.f, 0.f, 0.f};
        {
            uint4 st[3][4];
            uint4 av[2];
            av[0] = *(const uint4*)(aptr2);
#pragma unroll
            for (int ks = 0; ks < 16; ++ks) {
                if (ks + 1 < 16) av[(ks + 1) & 1] = *(const uint4*)(aptr2 + (ks + 1) * 32);
                bf16x8 a = as_bf16x8(av[ks & 1]);
#pragma unroll
                for (int nt = 0; nt < 4; ++nt) {
                    uint4 b = (ks < 10) ? w2r[ks * 4 + nt] : st[(ks - 10) % 3][nt];
                    acc2[nt] = __builtin_amdgcn_mfma_f32_16x16x32_bf16(a, as_bf16x8(b), acc2[nt], 0, 0, 0);
                }
                // prefetch streamed chunk ks+3 (issued after use to avoid WAR on slot reuse)
                if (ks >= 7 && ks < 13) {
                    int tc = ks + 3;
                    int slot = (tc - 10) % 3;
#pragma unroll
                    for (int nt = 0; nt < 4; ++nt)
                        st[slot][nt] = *(const uint4*)(w2slab + (tc * 4 + nt) * 512);
                }
            }
        }
#pragma unroll
        for (int nt = 0; nt < 4; ++nt)
#pragma unroll
            for (int j = 0; j < 4; ++j)
                sw[(q * 4 + j) * SCRS + nt * 16 + c16] = f2bf(acc2[nt][j]);
        __syncthreads();  // B3

        // ---------- gates 2 ----------
#pragma unroll
        for (int j = 0; j < 4; ++j) {
            int r = q * 4 + j;
            ushort4 zz = *(const ushort4*)(sw + r * SCRS + ul * 4);
            float gf = fast_sigmoid(bf2f(zz.x) + b2f0);
            float gi = fast_sigmoid(bf2f(zz.y) + b2f1);
            float gc = fast_tanh(bf2f(zz.z) + b2f2);
            float go = fast_sigmoid(bf2f(zz.w) + b2f3);
            float cn = gf * c2s[j] + gi * gc;
            c2s[j] = cn;
            hx2[r * HX2S + U] = f2bf(go * fast_tanh(cn));
        }
        // scr is wave-private; hx hazards ordered by B1/B2 of next iteration.
    }
    __syncthreads();

    // ---------- output: sigmoid(h2 @ w_out + b_out), fp32 store ----------
    if (tid < 512) {
        int rr = tid >> 5, s = tid & 31;
        uint4 hv = *(const uint4*)(hx2 + rr * HX2S + s * 8);
        uint4 wv = *(const uint4*)(wob + s * 8);
        const u16* hp = (const u16*)&hv;
        const u16* wp = (const u16*)&wv;
        float dot = 0.f;
#pragma unroll
        for (int i = 0; i < 8; ++i) dot += bf2f(hp[i]) * bf2f(wp[i]);
        float* psum = (float*)scr;
        psum[rr * 32 + s] = dot;
    }
    __syncthreads();
    if (tid < 16) {
        float* psum = (float*)scr;
        float ssum = 0.f;
        for (int i = 0; i < 32; ++i) ssum += psum[tid * 32 + i];
        out[row0 + tid] = fast_sigmoid(ssum + bf2f(bob[0]));
    }
}

extern "C" void kernel_launch(void* const* d_in, const int* in_sizes, int n_in,
                              void* d_out, int out_size, void* d_ws, size_t ws_size,
                              hipStream_t stream) {
    const int* tokens = (const int*)d_in[0];
    const void* emb = d_in[1];
    const void* wf1 = d_in[2];  const void* bf1_ = d_in[3];
    const void* wi1 = d_in[4];  const void* bi1_ = d_in[5];
    const void* wc1 = d_in[6];  const void* bc1_ = d_in[7];
    const void* wo1 = d_in[8];  const void* bo1_ = d_in[9];
    const void* wf2 = d_in[10]; const void* bf2_ = d_in[11];
    const void* wi2 = d_in[12]; const void* bi2_ = d_in[13];
    const void* wc2 = d_in[14]; const void* bc2_ = d_in[15];
    const void* wo2 = d_in[16]; const void* bo2_ = d_in[17];
    const void* w_out = d_in[18];
    const void* b_out = d_in[19];

    u16* wp1 = (u16*)d_ws;                 // 16*12*4*512 = 393216 u16
    u16* wp2 = wp1 + 16 * 12 * 4 * 512;    // 16*16*4*512 = 524288 u16
    u16* b1p = wp2 + 16 * 16 * 4 * 512;    // 1024
    u16* b2p = b1p + 1024;                 // 1024
    u16* wob = b2p + 1024;                 // 256
    u16* bob = wob + 256;                  // 8 (pad, keeps 16B align)
    u16* xd  = bob + 8;                    // 64*80*16*100 = 8,192,000 u16 (~16.4 MB)

    pack_w<<<dim3(16 * 12), dim3(256), 0, stream>>>(wf1, wi1, wc1, wo1, bf1_, bi1_, bc1_, bo1_,
                                                    wp1, b1p, 356, 12);
    pack_w<<<dim3(16 * 16), dim3(256), 0, stream>>>(wf2, wi2, wc2, wo2, bf2_, bi2_, bc2_, bo2_,
                                                    wp2, b2p, 512, 16);
    pack_out<<<dim3(1), dim3(256), 0, stream>>>(w_out, b_out, wob, bob);
    pregather_x<<<dim3(64), dim3(512), 0, stream>>>(tokens, emb, xd);
    lstm_kernel<<<dim3(64), dim3(1024), 0, stream>>>(xd, wp1, b1p, wp2, b2p,
                                                     wob, bob, (float*)d_out);
}